// Round 3
// baseline (1258.392 us; speedup 1.0000x reference)
//
#include <hip/hip_runtime.h>
#include <math.h>

#define NUSER 20000
#define NITEM 20000
#define NNODE 40000
#define MP_USER 20096   // 314*64
#define MP_NODE 40064   // 626*64 = 313*128

typedef unsigned short u16;
typedef __attribute__((ext_vector_type(8))) short bf16x8;   // 8 bf16 = 4 VGPRs
typedef __attribute__((ext_vector_type(4))) float f32x4;

__device__ __forceinline__ float leaky(float v){ return v > 0.0f ? v : 0.01f*v; }
__device__ __forceinline__ u16 f2bf(float f){
  unsigned u = __float_as_uint(f);
  return (u16)((u + 0x7FFFu + ((u>>16)&1u)) >> 16);   // RNE bf16
}
__device__ __forceinline__ float bf2f(u16 h){ return __uint_as_float(((unsigned)h)<<16); }
__device__ __forceinline__ unsigned pack2(u16 a, u16 b){ return (unsigned)a | ((unsigned)b<<16); }

// async global->LDS DMA, 16B per lane; LDS dest = wave-uniform base + lane*16
__device__ __forceinline__ void gll16(const u16* g, u16* l) {
  __builtin_amdgcn_global_load_lds((const __attribute__((address_space(1))) void*)g,
                                   (__attribute__((address_space(3))) void*)l, 16, 0, 0);
}

enum { EPI_STORE=0, EPI_TANH=1, EPI_LEAKY_ADD=2, EPI_ACCUM=3, EPI_NONE=4 };

// ================= MFMA GEMM: C[M,N] = epi(A[M,K] @ W[K,N]) =================
// R3: T3-minimal 2-phase pipeline. Double-buffered LDS; u16 operands staged via
// global_load_lds (linear LDS dest + inverse-XOR-swizzled per-lane global source,
// rule #21), fp32 A staged via in-iteration register prefetch (R0-style arrays,
// constexpr indices only — R1's lambda/cross-region arrays went to scratch).
// Per iter: issue tile t+1 loads -> ds_read+MFMA on tile t -> convert/write A ->
// one barrier. Load latency hides under MFMA instead of a per-step vmcnt(0) drain.
// LDS granule (kk,q) holds row q^(kk<<1); frag read G=(kg*BX + (row^(kg<<1)))*8.
// SPLITK>1: EPI_NONE partials at C + z*MP_USER*N (padded rows, no guards).
template<int WR, int WC, int MI, int EPI, bool ASPLIT, int SPLITK>
__global__ __launch_bounds__(WR*WC*64)
void wgemm_k(const float* __restrict__ A, const u16* __restrict__ Ah, const u16* __restrict__ Al,
             const u16* __restrict__ Bh, const u16* __restrict__ Bl,
             const float* __restrict__ bias, const float* __restrict__ add,
             float* __restrict__ C, int M, int N, int K, int Kp)
{
  constexpr int BM = WR*MI*16, BN = WC*64, T = WR*WC*64, NI = 4;
  constexpr int AG = BM*4, BG = BN*4;        // 8-u16 granules per k-tile (per hi/lo)
  constexpr int AITF = AG/T;                 // fp32-A granules per thread
  constexpr int AIT2 = 2*AG/T;               // split-A granule rounds (hi+lo)
  constexpr int BIT2 = 2*BG/T;               // B granule rounds (hi+lo)
  constexpr int LBM = (BM==64)?6:7;
  constexpr int LBN = (BN==64)?6:((BN==128)?7:8);
  __shared__ u16 Ash[2][4*BM*8], Asl[2][4*BM*8], Bsh[2][4*BN*8], Bsl[2][4*BN*8];
  const int tid = threadIdx.x, lane = tid & 63, wid = tid >> 6;
  const int wrow = wid / WC, wcol = wid % WC;
  const int row0 = blockIdx.y*BM;
  const int fr = lane & 15, kg = lane >> 4;
  const int Kc = Kp / SPLITK;
  const int ks0 = (SPLITK > 1) ? blockIdx.z * Kc : 0;

  f32x4 acc[MI][NI] = {};

// ---- staging macros (no lambdas: keep arrays promotable to VGPRs) ----
#define ASTAGE_GLL(KT, NB) do { \
  _Pragma("unroll") \
  for (int i_ = 0; i_ < AIT2; i_++) { \
    int gb_ = i_*T + wid*64; \
    bool hi_ = gb_ < AG; \
    int gl_ = gb_ + lane; \
    int gi_ = hi_ ? gl_ : gl_ - AG; \
    int q_ = gi_ & (BM-1), kk_ = gi_ >> LBM; \
    int r_ = q_ ^ (kk_<<1); \
    const u16* s_ = (hi_ ? Ah : Al) + (size_t)(row0+r_)*Kp + ks0 + (KT) + kk_*8; \
    u16* d_ = hi_ ? &Ash[NB][(gb_)*8] : &Asl[NB][(gb_-AG)*8]; \
    gll16(s_, d_); \
  } } while(0)

#define BSTAGE_GLL(KT, NB) do { \
  _Pragma("unroll") \
  for (int i_ = 0; i_ < BIT2; i_++) { \
    int gb_ = i_*T + wid*64; \
    bool hi_ = gb_ < BG; \
    int gl_ = gb_ + lane; \
    int gi_ = hi_ ? gl_ : gl_ - BG; \
    int q_ = gi_ & (BN-1), kk_ = gi_ >> LBN; \
    int r_ = q_ ^ (kk_<<1); \
    const u16* s_ = (hi_ ? Bh : Bl) + (size_t)r_*Kp + ks0 + (KT) + kk_*8; \
    u16* d_ = hi_ ? &Bsh[NB][(gb_)*8] : &Bsl[NB][(gb_-BG)*8]; \
    gll16(s_, d_); \
  } } while(0)

#define ALOADF(KT) do { \
  _Pragma("unroll") \
  for (int i_ = 0; i_ < AITF; i_++) { \
    int g_ = tid + i_*T; \
    int r_ = g_ >> 2, kk_ = g_ & 3; \
    int gr_ = row0 + r_, gk_ = ks0 + (KT) + kk_*8; \
    if (gr_ < M && gk_ + 8 <= K) { \
      *(float4*)&fv[i_][0] = *(const float4*)(A + (size_t)gr_*K + gk_); \
      *(float4*)&fv[i_][4] = *(const float4*)(A + (size_t)gr_*K + gk_ + 4); \
    } else { \
      _Pragma("unroll") \
      for (int j_=0;j_<8;j_++) fv[i_][j_] = (gr_ < M && gk_ + j_ < K) ? A[(size_t)gr_*K + gk_ + j_] : 0.f; \
    } \
  } } while(0)

#define ACONVW(NB) do { \
  _Pragma("unroll") \
  for (int i_ = 0; i_ < AITF; i_++) { \
    int g_ = tid + i_*T; \
    int r_ = g_ >> 2, kk_ = g_ & 3; \
    u16 hs_[8], ls_[8]; \
    _Pragma("unroll") \
    for (int j_=0;j_<8;j_++){ u16 h_ = f2bf(fv[i_][j_]); hs_[j_]=h_; ls_[j_]=f2bf(fv[i_][j_]-bf2f(h_)); } \
    int G_ = (kk_*BM + (r_ ^ (kk_<<1)))*8; \
    *(uint4*)&Ash[NB][G_] = make_uint4(pack2(hs_[0],hs_[1]),pack2(hs_[2],hs_[3]),pack2(hs_[4],hs_[5]),pack2(hs_[6],hs_[7])); \
    *(uint4*)&Asl[NB][G_] = make_uint4(pack2(ls_[0],ls_[1]),pack2(ls_[2],ls_[3]),pack2(ls_[4],ls_[5]),pack2(ls_[6],ls_[7])); \
  } } while(0)

  // ---- prologue: stage tile 0 into buffer 0 ----
  {
    float fv[AITF][8];
    if (ASPLIT) { ASTAGE_GLL(0, 0); }
    else        { ALOADF(0); ACONVW(0); }
    BSTAGE_GLL(0, 0);
  }
  __syncthreads();

  int cur = 0;
  for (int kt = 0; kt < Kc; kt += 32) {
    const int nb = cur ^ 1;
    const bool havenext = (kt + 32 < Kc);
    float fv[AITF][8];
    // phase 1: issue next-tile staging (loads fly during MFMA below)
    if (havenext) {
      if (ASPLIT) { ASTAGE_GLL(kt+32, nb); }
      else        { ALOADF(kt+32); }
      BSTAGE_GLL(kt+32, nb);
    }
    // phase 2: frags + MFMA from buf[cur]
    bf16x8 ah_[MI], al_[MI], bh_[NI], bl_[NI];
    #pragma unroll
    for (int mi=0;mi<MI;mi++){
      int rw = wrow*(MI*16) + mi*16 + fr;
      int G = (kg*BM + (rw ^ (kg<<1)))*8;
      ah_[mi] = *(const bf16x8*)&Ash[cur][G];
      al_[mi] = *(const bf16x8*)&Asl[cur][G];
    }
    #pragma unroll
    for (int ni=0;ni<NI;ni++){
      int cw = wcol*64 + ni*16 + fr;
      int G = (kg*BN + (cw ^ (kg<<1)))*8;
      bh_[ni] = *(const bf16x8*)&Bsh[cur][G];
      bl_[ni] = *(const bf16x8*)&Bsl[cur][G];
    }
    #pragma unroll
    for (int mi=0;mi<MI;mi++)
      #pragma unroll
      for (int ni=0;ni<NI;ni++){
        acc[mi][ni] = __builtin_amdgcn_mfma_f32_16x16x32_bf16(ah_[mi], bh_[ni], acc[mi][ni], 0,0,0);
        acc[mi][ni] = __builtin_amdgcn_mfma_f32_16x16x32_bf16(ah_[mi], bl_[ni], acc[mi][ni], 0,0,0);
        acc[mi][ni] = __builtin_amdgcn_mfma_f32_16x16x32_bf16(al_[mi], bh_[ni], acc[mi][ni], 0,0,0);
      }
    // phase 3: convert + write prefetched fp32 A (loads landed during MFMA)
    if (!ASPLIT && havenext) { ACONVW(nb); }
    __syncthreads();   // drains own vmcnt (gloads) + lgkm; next iter reads nb
    cur = nb;
  }
#undef ASTAGE_GLL
#undef BSTAGE_GLL
#undef ALOADF
#undef ACONVW

  // ---- epilogue: D reg r -> row=(lane>>4)*4+r, col=lane&15 (m89-verified) ----
  float* Cb = (EPI==EPI_NONE) ? (C + (size_t)blockIdx.z*MP_USER*N) : C;
  #pragma unroll
  for (int mi=0;mi<MI;mi++){
    #pragma unroll
    for (int ni=0;ni<NI;ni++){
      int col = wcol*64 + ni*16 + fr;
      if (EPI!=EPI_NONE && col >= N) continue;
      #pragma unroll
      for (int r=0;r<4;r++){
        int row = row0 + wrow*(MI*16) + mi*16 + kg*4 + r;
        if (EPI!=EPI_NONE && row >= M) continue;
        size_t idx = (size_t)row*N + col;
        float v = acc[mi][ni][r];
        if (EPI==EPI_NONE)           Cb[idx] = v;
        else if (EPI==EPI_STORE)     Cb[idx] = v;
        else if (EPI==EPI_TANH)      Cb[idx] = tanhf(v + bias[col]);
        else if (EPI==EPI_LEAKY_ADD) Cb[idx] = leaky(v + bias[col]) + add[idx];
        else                         Cb[idx] += leaky(v + bias[col] + add[idx]);
      }
    }
  }
}

// ============ weight pre-split: W[K][N] fp32 -> Wt_hi/Wt_lo[Np][Kp] bf16 ============
struct WDesc { const float* w; u16 *th, *tl; int K, N, Kp, Np; };
struct WPack { WDesc d[12]; };
__global__ void split_w_k(WPack P)
{
  WDesc D = P.d[blockIdx.y];
  int gid = blockIdx.x*256 + threadIdx.x;
  int tot = D.Np * D.Kp;
  if (gid >= tot) return;
  int k = gid / D.Np, n = gid % D.Np;
  float v = (k < D.K && n < D.N) ? D.w[(size_t)k*D.N + n] : 0.f;
  u16 h = f2bf(v);
  D.th[(size_t)n*D.Kp + k] = h;
  D.tl[(size_t)n*D.Kp + k] = f2bf(v - bf2f(h));
}

// ---------------- graph structure ----------------
// doubled edges: src(e)=ei[e]; dst(e)= e<E ? ei[e+E] : ei[e-E]
__global__ void count_deg(const int* __restrict__ ei, int* __restrict__ deg, int E)
{
  int e = blockIdx.x*blockDim.x + threadIdx.x;
  if (e >= 2*E) return;
  int dst = (e < E) ? ei[e+E] : ei[e-E];
  atomicAdd(&deg[dst], 1);
}

// wave-scan version: 1024 elems/iter, 2 barriers/iter
__global__ void scan_rowptr(const int* __restrict__ deg, int* __restrict__ row_ptr, int n)
{
  __shared__ int wsum[4];
  __shared__ int carry;
  int tid = threadIdx.x, lane = tid & 63, wid = tid >> 6;
  if (tid==0) carry = 0;
  __syncthreads();
  for (int base=0; base<n; base+=1024) {
    int i0 = base + tid*4;
    int d[4];
    #pragma unroll
    for (int k=0;k<4;k++) d[k] = (i0+k < n) ? deg[i0+k] : 0;
    int t = d[0]+d[1]+d[2]+d[3];
    int incl = t;
    #pragma unroll
    for (int o=1;o<64;o<<=1){ int v = __shfl_up(incl, o); if (lane >= o) incl += v; }
    if (lane==63) wsum[wid] = incl;
    __syncthreads();
    int pre = carry;
    for (int w=0; w<wid; w++) pre += wsum[w];
    int run = pre + incl - t;
    #pragma unroll
    for (int k=0;k<4;k++){ run += d[k]; if (i0+k < n) row_ptr[i0+k+1] = run; }
    __syncthreads();
    if (tid==0) carry += wsum[0]+wsum[1]+wsum[2]+wsum[3];
  }
  if (tid==0) row_ptr[0] = 0;
}

__global__ void fill_csr(const int* __restrict__ ei, const int* __restrict__ row_ptr,
                         int* __restrict__ row_fill, int* __restrict__ col_src,
                         int* __restrict__ col_dst, int E)
{
  int e = blockIdx.x*blockDim.x + threadIdx.x;
  if (e >= 2*E) return;
  int src = ei[e];
  int dst = (e < E) ? ei[e+E] : ei[e-E];
  int pos = row_ptr[dst] + atomicAdd(&row_fill[dst], 1);
  col_src[pos] = src;
  col_dst[pos] = dst;
}

// guarded vector row load
template<int VW>
__device__ __forceinline__ void loadrow(const float* __restrict__ r, int c0, int L, float* v){
  if (c0 + VW <= L) {
    if (VW==4) *(float4*)v = *(const float4*)r;
    else       *(float2*)v = *(const float2*)r;
  } else {
    #pragma unroll
    for (int j=0;j<VW;j++) v[j] = (c0+j < L) ? r[j] : 0.f;
  }
}

// ---------------- l2norm + bf16 split; folds mlp partial-sum reduce (nchunk, fixed
// order -> deterministic) + bias + tanh ----------------
// rows < NUSER: from pref; rows [NUSER,NNODE): tanh(sum_z xp_z + bias); pad rows: zero
template<int VW>
__global__ __launch_bounds__(256)
void l2norm_split_k(const float* __restrict__ pref, const float* __restrict__ xp,
                    const float* __restrict__ bias,
                    u16* __restrict__ xh, u16* __restrict__ xl, int L, int Kp, int nchunk)
{
  int row = (blockIdx.x*blockDim.x + threadIdx.x) >> 6;
  int lane = threadIdx.x & 63;
  if (row >= MP_NODE) return;
  int c0 = lane*VW;
  size_t ofs = (size_t)row*Kp + c0;
  if (row >= NNODE) {
    if (VW==4) { *(uint2*)&xh[ofs] = make_uint2(0,0); *(uint2*)&xl[ofs] = make_uint2(0,0); }
    else       { *(unsigned*)&xh[ofs] = 0; *(unsigned*)&xl[ofs] = 0; }
    return;
  }
  float v[VW];
  if (row < NUSER) {
    loadrow<VW>(pref + (size_t)row*L + c0, c0, L, v);
  } else {
    int i = row - NUSER;
    size_t po = (size_t)i*Kp + c0;   // xp padded to Kp cols, MP_USER rows per chunk
    float s[VW] = {};
    for (int z = 0; z < nchunk; z++) {
      float a[VW];
      const float* src = xp + (size_t)z*MP_USER*Kp + po;
      if (VW==4) *(float4*)a = *(const float4*)src;
      else       *(float2*)a = *(const float2*)src;
      #pragma unroll
      for (int j=0;j<VW;j++) s[j] += a[j];
    }
    #pragma unroll
    for (int j=0;j<VW;j++){
      int c = c0+j;
      float t = s[j] + ((c<L) ? bias[c] : 0.f);
      v[j] = (c<L) ? tanhf(t) : 0.f;
    }
  }
  float ss = 0.f;
  #pragma unroll
  for (int j=0;j<VW;j++) ss += v[j]*v[j];
  #pragma unroll
  for (int o=32;o;o>>=1) ss += __shfl_xor(ss, o);
  float inv = 1.0f / fmaxf(sqrtf(ss), 1e-12f);
  u16 hs[VW], ls[VW];
  #pragma unroll
  for (int j=0;j<VW;j++){
    float val = (c0+j < L) ? v[j]*inv : 0.f;
    hs[j] = f2bf(val); ls[j] = f2bf(val - bf2f(hs[j]));
  }
  if (VW==4) { *(uint2*)&xh[ofs] = make_uint2(pack2(hs[0],hs[1]),pack2(hs[2],hs[3]));
               *(uint2*)&xl[ofs] = make_uint2(pack2(ls[0],ls[1]),pack2(ls[2],ls[3])); }
  else       { *(unsigned*)&xh[ofs] = pack2(hs[0],hs[1]); *(unsigned*)&xl[ofs] = pack2(ls[0],ls[1]); }
}

// ---------------- edge-parallel logits over CSR slots: 16 lanes per edge ----------------
__global__ __launch_bounds__(256)
void edge_logits_k(const float* __restrict__ xw, const int* __restrict__ col_src,
                   const int* __restrict__ col_dst, const int* __restrict__ deg,
                   float* __restrict__ logits, int L, int E2)
{
  int p = (blockIdx.x*blockDim.x + threadIdx.x) >> 4;
  int j = threadIdx.x & 15;
  if (p >= E2) return;
  int src = col_src[p], dst = col_dst[p];
  const float* ps = xw + (size_t)src*L;
  const float* pd = xw + (size_t)dst*L;
  float dot = 0.f;
  for (int c = j*4; c < L; c += 64) {
    float4 a = *(const float4*)(ps + c);
    float4 b = *(const float4*)(pd + c);
    dot += a.x*b.x + a.y*b.y + a.z*b.z + a.w*b.w;
  }
  #pragma unroll
  for (int o=8;o;o>>=1) dot += __shfl_xor(dot, o, 16);
  if (j==0) {
    float t = dot / sqrtf((float)deg[src]);
    float gate = 1.0f/(1.0f + expf(-t));
    logits[p] = dot * gate;
  }
}

// ---------------- per-dst softmax over contiguous CSR range ----------------
__global__ __launch_bounds__(256)
void node_softmax(const float* __restrict__ logits, const int* __restrict__ row_ptr,
                  float* __restrict__ alpha, int n)
{
  int node = (blockIdx.x*blockDim.x + threadIdx.x) >> 6;
  int lane = threadIdx.x & 63;
  if (node >= n) return;
  int s = row_ptr[node], e = row_ptr[node+1];
  int cnt = e - s;
  if (cnt == 0) return;
  if (cnt <= 64) {
    float lv = (lane < cnt) ? logits[s+lane] : -INFINITY;
    float m = lv;
    #pragma unroll
    for (int o=32;o;o>>=1) m = fmaxf(m, __shfl_xor(m, o));
    float el = (lane < cnt) ? expf(lv - m) : 0.f;
    float d = el;
    #pragma unroll
    for (int o=32;o;o>>=1) d += __shfl_xor(d, o);
    if (lane < cnt) alpha[s+lane] = el / fmaxf(d, 1e-16f);
  } else {
    float m = -INFINITY;
    for (int q=s+lane;q<e;q+=64) m = fmaxf(m, logits[q]);
    #pragma unroll
    for (int o=32;o;o>>=1) m = fmaxf(m, __shfl_xor(m, o));
    float d = 0.f;
    for (int q=s+lane;q<e;q+=64) d += expf(logits[q]-m);
    #pragma unroll
    for (int o=32;o;o>>=1) d += __shfl_xor(d, o);
    float inv = 1.0f / fmaxf(d, 1e-16f);
    for (int q=s+lane;q<e;q+=64) alpha[q] = expf(logits[q]-m)*inv;
  }
}

// ---------------- aggregate -> h (bf16 split), one wave per node ----------------
template<int VW>
__global__ __launch_bounds__(256)
void aggregate_k(const float* __restrict__ xw, const float* __restrict__ alpha,
                 const int* __restrict__ row_ptr, const int* __restrict__ col_src,
                 const float* __restrict__ bias, u16* __restrict__ hh, u16* __restrict__ hl,
                 int L, int Kp)
{
  int node = (blockIdx.x*blockDim.x + threadIdx.x) >> 6;
  int lane = threadIdx.x & 63;
  if (node >= MP_NODE) return;
  int c0 = lane*VW;
  size_t ofs = (size_t)node*Kp + c0;
  if (node >= NNODE) {
    if (VW==4) { *(uint2*)&hh[ofs] = make_uint2(0,0); *(uint2*)&hl[ofs] = make_uint2(0,0); }
    else       { *(unsigned*)&hh[ofs] = 0; *(unsigned*)&hl[ofs] = 0; }
    return;
  }
  float acc[VW] = {};
  int s = row_ptr[node], e = row_ptr[node+1];
  for (int p=s;p<e;p++) {
    float a = alpha[p];
    float v[VW];
    loadrow<VW>(xw + (size_t)col_src[p]*L + c0, c0, L, v);
    #pragma unroll
    for (int j=0;j<VW;j++) acc[j] = fmaf(a, v[j], acc[j]);
  }
  float t[VW], ss = 0.f;
  #pragma unroll
  for (int j=0;j<VW;j++){ int c = c0+j; t[j] = (c<L) ? acc[j]+bias[c] : 0.f; ss += t[j]*t[j]; }
  #pragma unroll
  for (int o=32;o;o>>=1) ss += __shfl_xor(ss, o);
  float inv = 1.0f / fmaxf(sqrtf(ss), 1e-12f);
  u16 hs[VW], ls[VW];
  #pragma unroll
  for (int j=0;j<VW;j++){
    float o2 = (c0+j < L) ? leaky(t[j]*inv) : 0.f;
    hs[j] = f2bf(o2); ls[j] = f2bf(o2 - bf2f(hs[j]));
  }
  if (VW==4) { *(uint2*)&hh[ofs] = make_uint2(pack2(hs[0],hs[1]),pack2(hs[2],hs[3]));
               *(uint2*)&hl[ofs] = make_uint2(pack2(ls[0],ls[1]),pack2(ls[2],ls[3])); }
  else       { *(unsigned*)&hh[ofs] = pack2(hs[0],hs[1]); *(unsigned*)&hl[ofs] = pack2(ls[0],ls[1]); }
}

// scores: rep holds 3*rep_true -> scale dot by 1/9
__global__ __launch_bounds__(256)
void score_k(const float* __restrict__ rep, const int* __restrict__ un,
             const int* __restrict__ pi, const int* __restrict__ ni, float* __restrict__ out)
{
  int wid = (blockIdx.x*blockDim.x + threadIdx.x) >> 6;
  int lane = threadIdx.x & 63;
  if (wid >= 2048) return;
  int i = wid & 1023;
  int isneg = wid >> 10;
  int u = un[i];
  int it = isneg ? ni[i] : pi[i];
  float p = rep[(size_t)u*64 + lane] * rep[(size_t)it*64 + lane];
  #pragma unroll
  for (int o=32;o;o>>=1) p += __shfl_xor(p, o);
  if (lane==0) out[isneg*1024 + i] = p * (1.0f/9.0f);
}

// ---------------- launch ----------------
static inline size_t align_up(size_t v){ return (v + 255) & ~(size_t)255; }
static inline int cdiv(int a, int b){ return (a + b - 1) / b; }

extern "C" void kernel_launch(void* const* d_in, const int* in_sizes, int n_in,
                              void* d_out, int out_size, void* d_ws, size_t ws_size,
                              hipStream_t stream)
{
  const int E  = in_sizes[31] / 2;   // 250000
  const int E2 = 2*E;

  char* p = (char*)d_ws;
  auto carve = [&](size_t bytes){ char* r = p; p += align_up(bytes); return r; };
  // xp (split-K partials, up to 4 chunks) is dead before the conv GEMM writes xw,
  // so they alias: one 82.3MB union region.
  float* xw     = (float*)carve((size_t)4*MP_USER*256*4);
  float* xp     = xw;
  u16*   xh     = (u16*)carve((size_t)MP_NODE*256*2);
  u16*   xl     = (u16*)carve((size_t)MP_NODE*256*2);
  float* xhat   = (float*)carve((size_t)NNODE*64*4);
  float* rep    = (float*)carve((size_t)NNODE*64*4);
  float* logits = (float*)carve((size_t)E2*4);
  float* alpha  = (float*)carve((size_t)E2*4);
  int* deg      = (int*)carve((size_t)NNODE*4);
  int* row_ptr  = (int*)carve((size_t)(NNODE+1)*4);
  int* row_fill = (int*)carve((size_t)NNODE*4);
  int* col_src  = (int*)carve((size_t)E2*4);
  int* col_dst  = (int*)carve((size_t)E2*4);

  const int* ei = (const int*)d_in[31];
  const float* id_emb = (const float*)d_in[30];

  struct Mod { const float *feat,*pref,*mlp_w,*mlp_b,*conv_w,*conv_b,*lin_w,*lin_b,*g_w,*g_b;
               int Fd, L, Kpx, Kpf, NpL; };
  Mod md[3];
  for (int m=0;m<3;m++) {
    int b = m*10;
    md[m].feat   = (const float*)d_in[b+0];
    md[m].pref   = (const float*)d_in[b+1];
    md[m].mlp_w  = (const float*)d_in[b+2];
    md[m].mlp_b  = (const float*)d_in[b+3];
    md[m].conv_w = (const float*)d_in[b+4];
    md[m].conv_b = (const float*)d_in[b+5];
    md[m].lin_w  = (const float*)d_in[b+6];
    md[m].lin_b  = (const float*)d_in[b+7];
    md[m].g_w    = (const float*)d_in[b+8];
    md[m].g_b    = (const float*)d_in[b+9];
  }
  md[0].Fd=2048; md[0].L=256; md[0].Kpx=256; md[0].Kpf=2048; md[0].NpL=256;
  md[1].Fd=128;  md[1].L=128; md[1].Kpx=128; md[1].Kpf=128;  md[1].NpL=128;
  md[2].Fd=100;  md[2].L=100; md[2].Kpx=128; md[2].Kpf=128;  md[2].NpL=128;

  u16 *wmh[3],*wml[3],*wch[3],*wcl[3],*wlh[3],*wll[3],*wgh[3],*wgl[3];
  WPack P;
  int maxTot = 0;
  for (int m=0;m<3;m++) {
    const Mod& M_ = md[m];
    size_t smlp = (size_t)M_.NpL*M_.Kpf*2, sconv = (size_t)M_.NpL*M_.Kpx*2, slin = (size_t)64*M_.Kpx*2;
    wmh[m]=(u16*)carve(smlp); wml[m]=(u16*)carve(smlp);
    wch[m]=(u16*)carve(sconv); wcl[m]=(u16*)carve(sconv);
    wlh[m]=(u16*)carve(slin);  wll[m]=(u16*)carve(slin);
    wgh[m]=(u16*)carve(slin);  wgl[m]=(u16*)carve(slin);
    P.d[m*4+0] = { M_.mlp_w,  wmh[m], wml[m], M_.Fd, M_.L, M_.Kpf, M_.NpL };
    P.d[m*4+1] = { M_.conv_w, wch[m], wcl[m], M_.L,  M_.L, M_.Kpx, M_.NpL };
    P.d[m*4+2] = { M_.lin_w,  wlh[m], wll[m], M_.L,  64,   M_.Kpx, 64 };
    P.d[m*4+3] = { M_.g_w,    wgh[m], wgl[m], M_.L,  64,   M_.Kpx, 64 };
    for (int q=0;q<4;q++){ int t = P.d[m*4+q].Np*P.d[m*4+q].Kp; if (t>maxTot) maxTot=t; }
  }

  hipMemsetAsync(deg, 0, (size_t)NNODE*4, stream);
  hipMemsetAsync(row_fill, 0, (size_t)NNODE*4, stream);
  hipMemsetAsync(rep, 0, (size_t)NNODE*64*4, stream);

  { dim3 g(cdiv(maxTot,256), 12); split_w_k<<<g,256,0,stream>>>(P); }
  {
    int blocks = cdiv(E2, 256);
    count_deg<<<blocks,256,0,stream>>>(ei, deg, E);
    scan_rowptr<<<1,256,0,stream>>>(deg, row_ptr, NNODE);
    fill_csr<<<blocks,256,0,stream>>>(ei, row_ptr, row_fill, col_src, col_dst, E);
  }

  for (int m=0;m<3;m++) {
    const Mod& M_ = md[m];
    const int L = M_.L;

    // mlp partials: xp[chunk] = feat @ mlp_w (chunk of K); SPLITK boosts occupancy
    if (m == 0)
      wgemm_k<1,4,4,EPI_NONE,false,4><<<dim3(1,MP_USER/64,4),256,0,stream>>>(
          M_.feat, nullptr, nullptr, wmh[m], wml[m], nullptr, nullptr,
          xp, NUSER, 256, M_.Fd, M_.Kpf);
    else
      wgemm_k<1,2,4,EPI_NONE,false,2><<<dim3(1,MP_USER/64,2),128,0,stream>>>(
          M_.feat, nullptr, nullptr, wmh[m], wml[m], nullptr, nullptr,
          xp, NUSER, 128, M_.Fd, M_.Kpf);

    // l2norm + reduce partials + bias + tanh -> xh/xl
    {
      int nchunk = (m==0) ? 4 : 2;
      if (M_.Kpx==256) l2norm_split_k<4><<<MP_NODE/4,256,0,stream>>>(M_.pref, xp, M_.mlp_b, xh, xl, L, M_.Kpx, nchunk);
      else             l2norm_split_k<2><<<MP_NODE/4,256,0,stream>>>(M_.pref, xp, M_.mlp_b, xh, xl, L, M_.Kpx, nchunk);
    }

    // xw = x @ conv_w
    if (m == 0)
      wgemm_k<1,4,4,EPI_STORE,true,1><<<dim3(1,MP_NODE/64,1),256,0,stream>>>(
          nullptr, xh, xl, wch[m], wcl[m], nullptr, nullptr, xw, NNODE, L, L, M_.Kpx);
    else
      wgemm_k<1,2,4,EPI_STORE,true,1><<<dim3(1,MP_NODE/64,1),128,0,stream>>>(
          nullptr, xh, xl, wch[m], wcl[m], nullptr, nullptr, xw, NNODE, L, L, M_.Kpx);

    // xhat = leaky(x @ lin_w + b) + id_emb
    wgemm_k<4,1,2,EPI_LEAKY_ADD,true,1><<<dim3(1,MP_NODE/128,1),256,0,stream>>>(
        nullptr, xh, xl, wlh[m], wll[m], M_.lin_b, id_emb, xhat, NNODE, 64, L, M_.Kpx);

    // edge phase: edge-parallel logits -> node softmax -> aggregate
    edge_logits_k<<<cdiv(E2*16,256),256,0,stream>>>(xw, col_src, col_dst, deg, logits, L, E2);
    node_softmax<<<cdiv(NNODE*64,256),256,0,stream>>>(logits, row_ptr, alpha, NNODE);
    if (M_.Kpx==256) aggregate_k<4><<<MP_NODE/4,256,0,stream>>>(xw, alpha, row_ptr, col_src, M_.conv_b, xh, xl, L, M_.Kpx);
    else             aggregate_k<2><<<MP_NODE/4,256,0,stream>>>(xw, alpha, row_ptr, col_src, M_.conv_b, xh, xl, L, M_.Kpx);

    // rep += leaky(h @ g_w + g_b + xhat)
    wgemm_k<4,1,2,EPI_ACCUM,true,1><<<dim3(1,MP_NODE/128,1),256,0,stream>>>(
        nullptr, xh, xl, wgh[m], wgl[m], M_.g_b, xhat, rep, NNODE, 64, L, M_.Kpx);
  }

  score_k<<<cdiv(2048*64,256),256,0,stream>>>(rep, (const int*)d_in[32], (const int*)d_in[33],
                                              (const int*)d_in[34], (float*)d_out);
}

// Round 4
// 1243.450 us; speedup vs baseline: 1.0120x; 1.0120x over previous
//
#include <hip/hip_runtime.h>
#include <math.h>

#define NUSER 20000
#define NITEM 20000
#define NNODE 40000
#define MP_USER 20096   // 314*64
#define MP_NODE 40064   // 626*64 = 313*128

typedef unsigned short u16;
typedef __attribute__((ext_vector_type(8))) short bf16x8;   // 8 bf16 = 4 VGPRs
typedef __attribute__((ext_vector_type(4))) float f32x4;

__device__ __forceinline__ float leaky(float v){ return v > 0.0f ? v : 0.01f*v; }
__device__ __forceinline__ u16 f2bf(float f){
  unsigned u = __float_as_uint(f);
  return (u16)((u + 0x7FFFu + ((u>>16)&1u)) >> 16);   // RNE bf16
}
__device__ __forceinline__ float bf2f(u16 h){ return __uint_as_float(((unsigned)h)<<16); }
__device__ __forceinline__ unsigned pack2(u16 a, u16 b){ return (unsigned)a | ((unsigned)b<<16); }

enum { EPI_STORE=0, EPI_TANH=1, EPI_LEAKY_ADD=2, EPI_ACCUM=3, EPI_NONE=4 };

// ================= MFMA GEMM: C[M,N] = epi(A[M,K] @ W[K,N]) =================
// R2-proven body (133us on m0 MLP). R3's dbuf+global_load_lds regressed: 80KB LDS
// halved residency (hbm 1322->920 GB/s) and __syncthreads' vmcnt(0) drained the
// prefetch anyway. Single buffer, inline staging, SPLITK for occupancy.
// XOR-swizzled LDS: granule(r,kk) at G = kk*BM + (r ^ (kk<<1)). BK=32.
// SPLITK>1: EPI_NONE partials at C + z*MP_USER*N (padded rows, no guards).
template<int WR, int WC, int MI, int EPI, bool ASPLIT, int SPLITK>
__global__ __launch_bounds__(WR*WC*64)
void wgemm_k(const float* __restrict__ A, const u16* __restrict__ Ah, const u16* __restrict__ Al,
             const u16* __restrict__ Bh, const u16* __restrict__ Bl,
             const float* __restrict__ bias, const float* __restrict__ add,
             float* __restrict__ C, int M, int N, int K, int Kp)
{
  constexpr int BM = WR*MI*16, BN = WC*64, T = WR*WC*64, NI = 4;
  __shared__ u16 Ash[4*BM*8], Asl[4*BM*8], Bsh[4*BN*8], Bsl[4*BN*8];
  const int tid = threadIdx.x, lane = tid & 63, wid = tid >> 6;
  const int wrow = wid / WC, wcol = wid % WC;
  const int row0 = blockIdx.y*BM;
  const int fr = lane & 15, kg = lane >> 4;
  const int Kc = Kp / SPLITK;
  const int ks0 = (SPLITK > 1) ? blockIdx.z * Kc : 0;

  f32x4 acc[MI][NI] = {};

  for (int kt = 0; kt < Kc; kt += 32) {
    // ---- stage A ----
    if (ASPLIT) {
      constexpr int AG = BM*4;
      #pragma unroll
      for (int i = 0; i < 2*AG/T; i++) {
        int g = tid + i*T;
        int gi = (g < AG) ? g : g - AG;
        int r = gi >> 2, kk = gi & 3;
        size_t ofs = (size_t)(row0+r)*Kp + ks0 + kt + kk*8;
        int G = (kk*BM + (r ^ (kk<<1)))*8;
        if (g < AG) *(uint4*)&Ash[G] = *(const uint4*)(Ah + ofs);
        else        *(uint4*)&Asl[G] = *(const uint4*)(Al + ofs);
      }
    } else {
      constexpr int AG = BM*4;   // 8-float granules
      #pragma unroll
      for (int i = 0; i < AG/T; i++) {
        int g = tid + i*T;
        int r = g >> 2, kk = g & 3;
        int gr = row0 + r, gk = ks0 + kt + kk*8;
        float fv[8];
        if (gr < M && gk + 8 <= K) {
          *(float4*)&fv[0] = *(const float4*)(A + (size_t)gr*K + gk);
          *(float4*)&fv[4] = *(const float4*)(A + (size_t)gr*K + gk + 4);
        } else {
          #pragma unroll
          for (int j=0;j<8;j++) fv[j] = (gr < M && gk + j < K) ? A[(size_t)gr*K + gk + j] : 0.f;
        }
        u16 hs[8], ls[8];
        #pragma unroll
        for (int j=0;j<8;j++){ u16 h = f2bf(fv[j]); hs[j]=h; ls[j]=f2bf(fv[j]-bf2f(h)); }
        int G = (kk*BM + (r ^ (kk<<1)))*8;
        *(uint4*)&Ash[G] = make_uint4(pack2(hs[0],hs[1]),pack2(hs[2],hs[3]),pack2(hs[4],hs[5]),pack2(hs[6],hs[7]));
        *(uint4*)&Asl[G] = make_uint4(pack2(ls[0],ls[1]),pack2(ls[2],ls[3]),pack2(ls[4],ls[5]),pack2(ls[6],ls[7]));
      }
    }
    // ---- stage B ----
    {
      constexpr int BG = BN*4;
      #pragma unroll
      for (int i = 0; i < 2*BG/T; i++) {
        int g = tid + i*T;
        int gi = (g < BG) ? g : g - BG;
        int r = gi >> 2, kk = gi & 3;
        size_t ofs = (size_t)r*Kp + ks0 + kt + kk*8;
        int G = (kk*BN + (r ^ (kk<<1)))*8;
        if (g < BG) *(uint4*)&Bsh[G] = *(const uint4*)(Bh + ofs);
        else        *(uint4*)&Bsl[G] = *(const uint4*)(Bl + ofs);
      }
    }
    __syncthreads();
    // ---- frags + MFMA ----
    bf16x8 ah_[MI], al_[MI], bh_[NI], bl_[NI];
    #pragma unroll
    for (int mi=0;mi<MI;mi++){
      int rw = wrow*(MI*16) + mi*16 + fr;
      int G = (kg*BM + (rw ^ (kg<<1)))*8;
      ah_[mi] = *(const bf16x8*)&Ash[G];
      al_[mi] = *(const bf16x8*)&Asl[G];
    }
    #pragma unroll
    for (int ni=0;ni<NI;ni++){
      int cw = wcol*64 + ni*16 + fr;
      int G = (kg*BN + (cw ^ (kg<<1)))*8;
      bh_[ni] = *(const bf16x8*)&Bsh[G];
      bl_[ni] = *(const bf16x8*)&Bsl[G];
    }
    #pragma unroll
    for (int mi=0;mi<MI;mi++)
      #pragma unroll
      for (int ni=0;ni<NI;ni++){
        acc[mi][ni] = __builtin_amdgcn_mfma_f32_16x16x32_bf16(ah_[mi], bh_[ni], acc[mi][ni], 0,0,0);
        acc[mi][ni] = __builtin_amdgcn_mfma_f32_16x16x32_bf16(ah_[mi], bl_[ni], acc[mi][ni], 0,0,0);
        acc[mi][ni] = __builtin_amdgcn_mfma_f32_16x16x32_bf16(al_[mi], bh_[ni], acc[mi][ni], 0,0,0);
      }
    __syncthreads();
  }
  // ---- epilogue: D reg r -> row=(lane>>4)*4+r, col=lane&15 (m89-verified) ----
  float* Cb = (EPI==EPI_NONE) ? (C + (size_t)blockIdx.z*MP_USER*N) : C;
  #pragma unroll
  for (int mi=0;mi<MI;mi++){
    #pragma unroll
    for (int ni=0;ni<NI;ni++){
      int col = wcol*64 + ni*16 + fr;
      if (EPI!=EPI_NONE && col >= N) continue;
      #pragma unroll
      for (int r=0;r<4;r++){
        int row = row0 + wrow*(MI*16) + mi*16 + kg*4 + r;
        if (EPI!=EPI_NONE && row >= M) continue;
        size_t idx = (size_t)row*N + col;
        float v = acc[mi][ni][r];
        if (EPI==EPI_NONE)           Cb[idx] = v;
        else if (EPI==EPI_STORE)     Cb[idx] = v;
        else if (EPI==EPI_TANH)      Cb[idx] = tanhf(v + bias[col]);
        else if (EPI==EPI_LEAKY_ADD) Cb[idx] = leaky(v + bias[col]) + add[idx];
        else                         Cb[idx] += leaky(v + bias[col] + add[idx]);
      }
    }
  }
}

// ============ weight pre-split: W[K][N] fp32 -> Wt_hi/Wt_lo[Np][Kp] bf16 ============
struct WDesc { const float* w; u16 *th, *tl; int K, N, Kp, Np; };
struct WPack { WDesc d[12]; };
__global__ void split_w_k(WPack P)
{
  WDesc D = P.d[blockIdx.y];
  int gid = blockIdx.x*256 + threadIdx.x;
  int tot = D.Np * D.Kp;
  if (gid >= tot) return;
  int k = gid / D.Np, n = gid % D.Np;
  float v = (k < D.K && n < D.N) ? D.w[(size_t)k*D.N + n] : 0.f;
  u16 h = f2bf(v);
  D.th[(size_t)n*D.Kp + k] = h;
  D.tl[(size_t)n*D.Kp + k] = f2bf(v - bf2f(h));
}

// ---------------- graph structure ----------------
// doubled edges: src(e)=ei[e]; dst(e)= e<E ? ei[e+E] : ei[e-E]
__global__ void count_deg(const int* __restrict__ ei, int* __restrict__ deg, int E)
{
  int e = blockIdx.x*blockDim.x + threadIdx.x;
  if (e >= 2*E) return;
  int dst = (e < E) ? ei[e+E] : ei[e-E];
  atomicAdd(&deg[dst], 1);
}

// wave-scan version: 1024 elems/iter, 2 barriers/iter
__global__ void scan_rowptr(const int* __restrict__ deg, int* __restrict__ row_ptr, int n)
{
  __shared__ int wsum[4];
  __shared__ int carry;
  int tid = threadIdx.x, lane = tid & 63, wid = tid >> 6;
  if (tid==0) carry = 0;
  __syncthreads();
  for (int base=0; base<n; base+=1024) {
    int i0 = base + tid*4;
    int d[4];
    #pragma unroll
    for (int k=0;k<4;k++) d[k] = (i0+k < n) ? deg[i0+k] : 0;
    int t = d[0]+d[1]+d[2]+d[3];
    int incl = t;
    #pragma unroll
    for (int o=1;o<64;o<<=1){ int v = __shfl_up(incl, o); if (lane >= o) incl += v; }
    if (lane==63) wsum[wid] = incl;
    __syncthreads();
    int pre = carry;
    for (int w=0; w<wid; w++) pre += wsum[w];
    int run = pre + incl - t;
    #pragma unroll
    for (int k=0;k<4;k++){ run += d[k]; if (i0+k < n) row_ptr[i0+k+1] = run; }
    __syncthreads();
    if (tid==0) carry += wsum[0]+wsum[1]+wsum[2]+wsum[3];
  }
  if (tid==0) row_ptr[0] = 0;
}

__global__ void fill_csr(const int* __restrict__ ei, const int* __restrict__ row_ptr,
                         int* __restrict__ row_fill, int* __restrict__ col_src, int E)
{
  int e = blockIdx.x*blockDim.x + threadIdx.x;
  if (e >= 2*E) return;
  int src = ei[e];
  int dst = (e < E) ? ei[e+E] : ei[e-E];
  int pos = row_ptr[dst] + atomicAdd(&row_fill[dst], 1);
  col_src[pos] = src;
}

// guarded vector row load
template<int VW>
__device__ __forceinline__ void loadrow(const float* __restrict__ r, int c0, int L, float* v){
  if (c0 + VW <= L) {
    if (VW==4) *(float4*)v = *(const float4*)r;
    else       *(float2*)v = *(const float2*)r;
  } else {
    #pragma unroll
    for (int j=0;j<VW;j++) v[j] = (c0+j < L) ? r[j] : 0.f;
  }
}

// ---------------- l2norm + bf16 split; folds mlp partial-sum reduce (nchunk, fixed
// order -> deterministic) + bias + tanh ----------------
// rows < NUSER: from pref; rows [NUSER,NNODE): tanh(sum_z xp_z + bias); pad rows: zero
template<int VW>
__global__ __launch_bounds__(256)
void l2norm_split_k(const float* __restrict__ pref, const float* __restrict__ xp,
                    const float* __restrict__ bias,
                    u16* __restrict__ xh, u16* __restrict__ xl, int L, int Kp, int nchunk)
{
  int row = (blockIdx.x*blockDim.x + threadIdx.x) >> 6;
  int lane = threadIdx.x & 63;
  if (row >= MP_NODE) return;
  int c0 = lane*VW;
  size_t ofs = (size_t)row*Kp + c0;
  if (row >= NNODE) {
    if (VW==4) { *(uint2*)&xh[ofs] = make_uint2(0,0); *(uint2*)&xl[ofs] = make_uint2(0,0); }
    else       { *(unsigned*)&xh[ofs] = 0; *(unsigned*)&xl[ofs] = 0; }
    return;
  }
  float v[VW];
  if (row < NUSER) {
    loadrow<VW>(pref + (size_t)row*L + c0, c0, L, v);
  } else {
    int i = row - NUSER;
    size_t po = (size_t)i*Kp + c0;   // xp padded to Kp cols, MP_USER rows per chunk
    float s[VW] = {};
    for (int z = 0; z < nchunk; z++) {
      float a[VW];
      const float* src = xp + (size_t)z*MP_USER*Kp + po;
      if (VW==4) *(float4*)a = *(const float4*)src;
      else       *(float2*)a = *(const float2*)src;
      #pragma unroll
      for (int j=0;j<VW;j++) s[j] += a[j];
    }
    #pragma unroll
    for (int j=0;j<VW;j++){
      int c = c0+j;
      float t = s[j] + ((c<L) ? bias[c] : 0.f);
      v[j] = (c<L) ? tanhf(t) : 0.f;
    }
  }
  float ss = 0.f;
  #pragma unroll
  for (int j=0;j<VW;j++) ss += v[j]*v[j];
  #pragma unroll
  for (int o=32;o;o>>=1) ss += __shfl_xor(ss, o);
  float inv = 1.0f / fmaxf(sqrtf(ss), 1e-12f);
  u16 hs[VW], ls[VW];
  #pragma unroll
  for (int j=0;j<VW;j++){
    float val = (c0+j < L) ? v[j]*inv : 0.f;
    hs[j] = f2bf(val); ls[j] = f2bf(val - bf2f(hs[j]));
  }
  if (VW==4) { *(uint2*)&xh[ofs] = make_uint2(pack2(hs[0],hs[1]),pack2(hs[2],hs[3]));
               *(uint2*)&xl[ofs] = make_uint2(pack2(ls[0],ls[1]),pack2(ls[2],ls[3])); }
  else       { *(unsigned*)&xh[ofs] = pack2(hs[0],hs[1]); *(unsigned*)&xl[ofs] = pack2(ls[0],ls[1]); }
}

// ============ fused edge phase: logits + softmax + aggregate, per dst node ============
// One wave per node (4/block). Phase 1: 4 edges in parallel (16 lanes/edge, EXACT
// edge_logits lane pattern: c=j*4 step 64, shfl_xor width-16 tree) computing logits
// while caching gathered xw[src] rows in LDS (i<CAP). Phase 2: in-wave softmax
// (EXACT node_softmax trees). Phase 3: aggregate in CSR order from cache (global
// fallback i>=CAP) + bias + l2norm + leaky + bf16 split (EXACT aggregate_k tail).
// Saves: 2nd ps-gather pass, per-edge pd redundancy, logits/alpha round trips.
// cnt>64 fallback via global logits (never triggers at Poisson-12.5 degrees).
template<int VW, int CAP, int LP>
__global__ __launch_bounds__(256)
void fused_edge_k(const float* __restrict__ xw, const int* __restrict__ row_ptr,
                  const int* __restrict__ col_src, const int* __restrict__ deg_,
                  const float* __restrict__ bias, float* __restrict__ glogits,
                  u16* __restrict__ hh, u16* __restrict__ hl, int L, int Kp)
{
  constexpr int KCH = (LP + 63)/64;
  __shared__ float cache[4][CAP][LP];
  __shared__ float lsl[4][64];
  const int slot = threadIdx.x >> 6;
  const int lane = threadIdx.x & 63;
  const int node = blockIdx.x*4 + slot;
  if (node >= MP_NODE) return;
  const int c0 = lane*VW;
  const size_t ofs = (size_t)node*Kp + c0;
  if (node >= NNODE) {
    if (VW==4) { *(uint2*)&hh[ofs] = make_uint2(0,0); *(uint2*)&hl[ofs] = make_uint2(0,0); }
    else       { *(unsigned*)&hh[ofs] = 0; *(unsigned*)&hl[ofs] = 0; }
    return;
  }
  const int s = row_ptr[node], e = row_ptr[node+1];
  const int cnt = e - s;
  const int sw = lane >> 4, j = lane & 15;
  const bool big = (cnt > 64);

  // dst row chunks for this sub-wave's dot lanes (same values edge_logits read)
  const float* pd = xw + (size_t)node*L;
  float4 pdv[KCH];
  #pragma unroll
  for (int k=0;k<KCH;k++){
    int c = j*4 + k*64;
    pdv[k] = (c < L) ? *(const float4*)(pd + c) : make_float4(0.f,0.f,0.f,0.f);
  }

  // ---- phase 1: logits (+ cache fill) ----
  int nit = (cnt + 3) >> 2;
  for (int it = 0; it < nit; it++) {
    int i = it*4 + sw;
    float dot = 0.f;
    int src = 0;
    if (i < cnt) {
      src = col_src[s+i];
      const float* ps = xw + (size_t)src*L;
      #pragma unroll
      for (int k=0;k<KCH;k++){
        int c = j*4 + k*64;
        if (c < L) {
          float4 a = *(const float4*)(ps + c);
          if (i < CAP) *(float4*)&cache[slot][i][c] = a;
          dot += a.x*pdv[k].x + a.y*pdv[k].y + a.z*pdv[k].z + a.w*pdv[k].w;
        }
      }
    }
    #pragma unroll
    for (int o=8;o;o>>=1) dot += __shfl_xor(dot, o, 16);
    if (i < cnt && j == 0) {
      float t = dot / sqrtf((float)deg_[src]);
      float gate = 1.0f/(1.0f + expf(-t));
      float lg = dot * gate;
      if (i < 64) lsl[slot][i] = lg;
      if (big) glogits[s+i] = lg;
    }
  }
  // within-wave LDS visibility (no block barrier: loops are node-divergent)
  asm volatile("s_waitcnt lgkmcnt(0)" ::: "memory");

  // ---- phase 2: softmax ----
  float alpha_r = 0.f, mxv = 0.f, sinv = 0.f;
  if (!big) {
    if (cnt > 0) {
      float lv = (lane < cnt) ? lsl[slot][lane] : -INFINITY;
      float m = lv;
      #pragma unroll
      for (int o=32;o;o>>=1) m = fmaxf(m, __shfl_xor(m, o));
      float el = (lane < cnt) ? expf(lv - m) : 0.f;
      float d = el;
      #pragma unroll
      for (int o=32;o;o>>=1) d += __shfl_xor(d, o);
      alpha_r = el / fmaxf(d, 1e-16f);
    }
  } else {
    asm volatile("s_waitcnt vmcnt(0)" ::: "memory");
    float m = -INFINITY;
    for (int q=s+lane;q<e;q+=64) m = fmaxf(m, glogits[q]);
    #pragma unroll
    for (int o=32;o;o>>=1) m = fmaxf(m, __shfl_xor(m, o));
    float d = 0.f;
    for (int q=s+lane;q<e;q+=64) d += expf(glogits[q]-m);
    #pragma unroll
    for (int o=32;o;o>>=1) d += __shfl_xor(d, o);
    mxv = m; sinv = 1.0f/fmaxf(d, 1e-16f);
  }

  // ---- phase 3: aggregate in CSR order ----
  float acc[VW] = {};
  for (int i = 0; i < cnt; i++) {
    float a = big ? (expf(glogits[s+i]-mxv)*sinv) : __shfl(alpha_r, i);
    float v[VW];
    if (i < CAP) {
      if (c0 + VW <= L) {
        if (VW==4) *(float4*)v = *(const float4*)&cache[slot][i][c0];
        else       *(float2*)v = *(const float2*)&cache[slot][i][c0];
      } else {
        #pragma unroll
        for (int jj=0;jj<VW;jj++) v[jj] = (c0+jj < L) ? cache[slot][i][c0+jj] : 0.f;
      }
    } else {
      loadrow<VW>(xw + (size_t)col_src[s+i]*L + c0, c0, L, v);
    }
    #pragma unroll
    for (int jj=0;jj<VW;jj++) acc[jj] = fmaf(a, v[jj], acc[jj]);
  }
  // ---- tail: bias + l2norm + leaky + bf16 split (aggregate_k-identical) ----
  float t[VW], ss = 0.f;
  #pragma unroll
  for (int jj=0;jj<VW;jj++){ int c = c0+jj; t[jj] = (c<L) ? acc[jj]+bias[c] : 0.f; ss += t[jj]*t[jj]; }
  #pragma unroll
  for (int o=32;o;o>>=1) ss += __shfl_xor(ss, o);
  float inv = 1.0f / fmaxf(sqrtf(ss), 1e-12f);
  u16 hs[VW], ls[VW];
  #pragma unroll
  for (int jj=0;jj<VW;jj++){
    float o2 = (c0+jj < L) ? leaky(t[jj]*inv) : 0.f;
    hs[jj] = f2bf(o2); ls[jj] = f2bf(o2 - bf2f(hs[jj]));
  }
  if (VW==4) { *(uint2*)&hh[ofs] = make_uint2(pack2(hs[0],hs[1]),pack2(hs[2],hs[3]));
               *(uint2*)&hl[ofs] = make_uint2(pack2(ls[0],ls[1]),pack2(ls[2],ls[3])); }
  else       { *(unsigned*)&hh[ofs] = pack2(hs[0],hs[1]); *(unsigned*)&hl[ofs] = pack2(ls[0],ls[1]); }
}

// scores: rep holds 3*rep_true -> scale dot by 1/9
__global__ __launch_bounds__(256)
void score_k(const float* __restrict__ rep, const int* __restrict__ un,
             const int* __restrict__ pi, const int* __restrict__ ni, float* __restrict__ out)
{
  int wid = (blockIdx.x*blockDim.x + threadIdx.x) >> 6;
  int lane = threadIdx.x & 63;
  if (wid >= 2048) return;
  int i = wid & 1023;
  int isneg = wid >> 10;
  int u = un[i];
  int it = isneg ? ni[i] : pi[i];
  float p = rep[(size_t)u*64 + lane] * rep[(size_t)it*64 + lane];
  #pragma unroll
  for (int o=32;o;o>>=1) p += __shfl_xor(p, o);
  if (lane==0) out[isneg*1024 + i] = p * (1.0f/9.0f);
}

// ---------------- launch ----------------
static inline size_t align_up(size_t v){ return (v + 255) & ~(size_t)255; }
static inline int cdiv(int a, int b){ return (a + b - 1) / b; }

extern "C" void kernel_launch(void* const* d_in, const int* in_sizes, int n_in,
                              void* d_out, int out_size, void* d_ws, size_t ws_size,
                              hipStream_t stream)
{
  const int E  = in_sizes[31] / 2;   // 250000
  const int E2 = 2*E;

  char* p = (char*)d_ws;
  auto carve = [&](size_t bytes){ char* r = p; p += align_up(bytes); return r; };
  // xp (split-K partials, up to 4 chunks) is dead before the conv GEMM writes xw,
  // so they alias: one 82.3MB union region.
  float* xw     = (float*)carve((size_t)4*MP_USER*256*4);
  float* xp     = xw;
  u16*   xh     = (u16*)carve((size_t)MP_NODE*256*2);
  u16*   xl     = (u16*)carve((size_t)MP_NODE*256*2);
  float* xhat   = (float*)carve((size_t)NNODE*64*4);
  float* rep    = (float*)carve((size_t)NNODE*64*4);
  float* logits = (float*)carve((size_t)E2*4);
  int* deg      = (int*)carve((size_t)NNODE*4);
  int* row_ptr  = (int*)carve((size_t)(NNODE+1)*4);
  int* row_fill = (int*)carve((size_t)NNODE*4);
  int* col_src  = (int*)carve((size_t)E2*4);

  const int* ei = (const int*)d_in[31];
  const float* id_emb = (const float*)d_in[30];

  struct Mod { const float *feat,*pref,*mlp_w,*mlp_b,*conv_w,*conv_b,*lin_w,*lin_b,*g_w,*g_b;
               int Fd, L, Kpx, Kpf, NpL; };
  Mod md[3];
  for (int m=0;m<3;m++) {
    int b = m*10;
    md[m].feat   = (const float*)d_in[b+0];
    md[m].pref   = (const float*)d_in[b+1];
    md[m].mlp_w  = (const float*)d_in[b+2];
    md[m].mlp_b  = (const float*)d_in[b+3];
    md[m].conv_w = (const float*)d_in[b+4];
    md[m].conv_b = (const float*)d_in[b+5];
    md[m].lin_w  = (const float*)d_in[b+6];
    md[m].lin_b  = (const float*)d_in[b+7];
    md[m].g_w    = (const float*)d_in[b+8];
    md[m].g_b    = (const float*)d_in[b+9];
  }
  md[0].Fd=2048; md[0].L=256; md[0].Kpx=256; md[0].Kpf=2048; md[0].NpL=256;
  md[1].Fd=128;  md[1].L=128; md[1].Kpx=128; md[1].Kpf=128;  md[1].NpL=128;
  md[2].Fd=100;  md[2].L=100; md[2].Kpx=128; md[2].Kpf=128;  md[2].NpL=128;

  u16 *wmh[3],*wml[3],*wch[3],*wcl[3],*wlh[3],*wll[3],*wgh[3],*wgl[3];
  WPack P;
  int maxTot = 0;
  for (int m=0;m<3;m++) {
    const Mod& M_ = md[m];
    size_t smlp = (size_t)M_.NpL*M_.Kpf*2, sconv = (size_t)M_.NpL*M_.Kpx*2, slin = (size_t)64*M_.Kpx*2;
    wmh[m]=(u16*)carve(smlp); wml[m]=(u16*)carve(smlp);
    wch[m]=(u16*)carve(sconv); wcl[m]=(u16*)carve(sconv);
    wlh[m]=(u16*)carve(slin);  wll[m]=(u16*)carve(slin);
    wgh[m]=(u16*)carve(slin);  wgl[m]=(u16*)carve(slin);
    P.d[m*4+0] = { M_.mlp_w,  wmh[m], wml[m], M_.Fd, M_.L, M_.Kpf, M_.NpL };
    P.d[m*4+1] = { M_.conv_w, wch[m], wcl[m], M_.L,  M_.L, M_.Kpx, M_.NpL };
    P.d[m*4+2] = { M_.lin_w,  wlh[m], wll[m], M_.L,  64,   M_.Kpx, 64 };
    P.d[m*4+3] = { M_.g_w,    wgh[m], wgl[m], M_.L,  64,   M_.Kpx, 64 };
    for (int q=0;q<4;q++){ int t = P.d[m*4+q].Np*P.d[m*4+q].Kp; if (t>maxTot) maxTot=t; }
  }

  hipMemsetAsync(deg, 0, (size_t)NNODE*4, stream);
  hipMemsetAsync(row_fill, 0, (size_t)NNODE*4, stream);
  hipMemsetAsync(rep, 0, (size_t)NNODE*64*4, stream);

  { dim3 g(cdiv(maxTot,256), 12); split_w_k<<<g,256,0,stream>>>(P); }
  {
    int blocks = cdiv(E2, 256);
    count_deg<<<blocks,256,0,stream>>>(ei, deg, E);
    scan_rowptr<<<1,256,0,stream>>>(deg, row_ptr, NNODE);
    fill_csr<<<blocks,256,0,stream>>>(ei, row_ptr, row_fill, col_src, E);
  }

  for (int m=0;m<3;m++) {
    const Mod& M_ = md[m];
    const int L = M_.L;

    // mlp partials: xp[chunk] = feat @ mlp_w (chunk of K); SPLITK boosts occupancy
    if (m == 0)
      wgemm_k<1,4,4,EPI_NONE,false,4><<<dim3(1,MP_USER/64,4),256,0,stream>>>(
          M_.feat, nullptr, nullptr, wmh[m], wml[m], nullptr, nullptr,
          xp, NUSER, 256, M_.Fd, M_.Kpf);
    else
      wgemm_k<1,2,4,EPI_NONE,false,2><<<dim3(1,MP_USER/64,2),128,0,stream>>>(
          M_.feat, nullptr, nullptr, wmh[m], wml[m], nullptr, nullptr,
          xp, NUSER, 128, M_.Fd, M_.Kpf);

    // l2norm + reduce partials + bias + tanh -> xh/xl
    {
      int nchunk = (m==0) ? 4 : 2;
      if (M_.Kpx==256) l2norm_split_k<4><<<MP_NODE/4,256,0,stream>>>(M_.pref, xp, M_.mlp_b, xh, xl, L, M_.Kpx, nchunk);
      else             l2norm_split_k<2><<<MP_NODE/4,256,0,stream>>>(M_.pref, xp, M_.mlp_b, xh, xl, L, M_.Kpx, nchunk);
    }

    // xw = x @ conv_w
    if (m == 0)
      wgemm_k<1,4,4,EPI_STORE,true,1><<<dim3(1,MP_NODE/64,1),256,0,stream>>>(
          nullptr, xh, xl, wch[m], wcl[m], nullptr, nullptr, xw, NNODE, L, L, M_.Kpx);
    else
      wgemm_k<1,2,4,EPI_STORE,true,1><<<dim3(1,MP_NODE/64,1),128,0,stream>>>(
          nullptr, xh, xl, wch[m], wcl[m], nullptr, nullptr, xw, NNODE, L, L, M_.Kpx);

    // xhat = leaky(x @ lin_w + b) + id_emb
    wgemm_k<4,1,2,EPI_LEAKY_ADD,true,1><<<dim3(1,MP_NODE/128,1),256,0,stream>>>(
        nullptr, xh, xl, wlh[m], wll[m], M_.lin_b, id_emb, xhat, NNODE, 64, L, M_.Kpx);

    // fused edge phase: logits + softmax + aggregate -> h (xh/xl)
    if (m == 0)
      fused_edge_k<4,12,256><<<MP_NODE/4,256,0,stream>>>(xw, row_ptr, col_src, deg, M_.conv_b, logits, xh, xl, L, M_.Kpx);
    else if (m == 1)
      fused_edge_k<2,20,128><<<MP_NODE/4,256,0,stream>>>(xw, row_ptr, col_src, deg, M_.conv_b, logits, xh, xl, L, M_.Kpx);
    else
      fused_edge_k<2,20,104><<<MP_NODE/4,256,0,stream>>>(xw, row_ptr, col_src, deg, M_.conv_b, logits, xh, xl, L, M_.Kpx);

    // rep += leaky(h @ g_w + g_b + xhat)
    wgemm_k<4,1,2,EPI_ACCUM,true,1><<<dim3(1,MP_NODE/128,1),256,0,stream>>>(
        nullptr, xh, xl, wgh[m], wgl[m], M_.g_b, xhat, rep, NNODE, 64, L, M_.Kpx);
  }

  score_k<<<cdiv(2048*64,256),256,0,stream>>>(rep, (const int*)d_in[32], (const int*)d_in[33],
                                              (const int*)d_in[34], (float*)d_out);
}

// Round 6
// 1009.373 us; speedup vs baseline: 1.2467x; 1.2319x over previous
//
#include <hip/hip_runtime.h>
#include <math.h>

#define NUSER 20000
#define NITEM 20000
#define NNODE 40000
#define MP_USER 20096   // 314*64
#define MP_NODE 40064   // 626*64 = 313*128

typedef unsigned short u16;
typedef __attribute__((ext_vector_type(8))) short bf16x8;   // 8 bf16 = 4 VGPRs
typedef __attribute__((ext_vector_type(4))) float f32x4;

__device__ __forceinline__ float leaky(float v){ return v > 0.0f ? v : 0.01f*v; }
__device__ __forceinline__ u16 f2bf(float f){
  unsigned u = __float_as_uint(f);
  return (u16)((u + 0x7FFFu + ((u>>16)&1u)) >> 16);   // RNE bf16
}
__device__ __forceinline__ float bf2f(u16 h){ return __uint_as_float(((unsigned)h)<<16); }
__device__ __forceinline__ unsigned pack2(u16 a, u16 b){ return (unsigned)a | ((unsigned)b<<16); }

enum { EPI_STORE=0, EPI_TANH=1, EPI_LEAKY_ADD=2, EPI_ACCUM=3, EPI_NONE=4 };

// ================= MFMA GEMM: C[M,N] = epi(A[M,K] @ W[K,N]) =================
// R2-proven body (133us on m0 MLP). R3's dbuf+global_load_lds regressed: 80KB LDS
// halved residency (hbm 1322->920 GB/s) and __syncthreads' vmcnt(0) drained the
// prefetch anyway. Single buffer, inline staging, SPLITK for occupancy.
// XOR-swizzled LDS: granule(r,kk) at G = kk*BM + (r ^ (kk<<1)). BK=32.
// SPLITK>1: EPI_NONE partials at C + z*MP_USER*N (padded rows, no guards).
template<int WR, int WC, int MI, int EPI, bool ASPLIT, int SPLITK>
__global__ __launch_bounds__(WR*WC*64)
void wgemm_k(const float* __restrict__ A, const u16* __restrict__ Ah, const u16* __restrict__ Al,
             const u16* __restrict__ Bh, const u16* __restrict__ Bl,
             const float* __restrict__ bias, const float* __restrict__ add,
             float* __restrict__ C, int M, int N, int K, int Kp)
{
  constexpr int BM = WR*MI*16, BN = WC*64, T = WR*WC*64, NI = 4;
  __shared__ u16 Ash[4*BM*8], Asl[4*BM*8], Bsh[4*BN*8], Bsl[4*BN*8];
  const int tid = threadIdx.x, lane = tid & 63, wid = tid >> 6;
  const int wrow = wid / WC, wcol = wid % WC;
  const int row0 = blockIdx.y*BM;
  const int fr = lane & 15, kg = lane >> 4;
  const int Kc = Kp / SPLITK;
  const int ks0 = (SPLITK > 1) ? blockIdx.z * Kc : 0;

  f32x4 acc[MI][NI] = {};

  for (int kt = 0; kt < Kc; kt += 32) {
    // ---- stage A ----
    if (ASPLIT) {
      constexpr int AG = BM*4;
      #pragma unroll
      for (int i = 0; i < 2*AG/T; i++) {
        int g = tid + i*T;
        int gi = (g < AG) ? g : g - AG;
        int r = gi >> 2, kk = gi & 3;
        size_t ofs = (size_t)(row0+r)*Kp + ks0 + kt + kk*8;
        int G = (kk*BM + (r ^ (kk<<1)))*8;
        if (g < AG) *(uint4*)&Ash[G] = *(const uint4*)(Ah + ofs);
        else        *(uint4*)&Asl[G] = *(const uint4*)(Al + ofs);
      }
    } else {
      constexpr int AG = BM*4;   // 8-float granules
      #pragma unroll
      for (int i = 0; i < AG/T; i++) {
        int g = tid + i*T;
        int r = g >> 2, kk = g & 3;
        int gr = row0 + r, gk = ks0 + kt + kk*8;
        float fv[8];
        if (gr < M && gk + 8 <= K) {
          *(float4*)&fv[0] = *(const float4*)(A + (size_t)gr*K + gk);
          *(float4*)&fv[4] = *(const float4*)(A + (size_t)gr*K + gk + 4);
        } else {
          #pragma unroll
          for (int j=0;j<8;j++) fv[j] = (gr < M && gk + j < K) ? A[(size_t)gr*K + gk + j] : 0.f;
        }
        u16 hs[8], ls[8];
        #pragma unroll
        for (int j=0;j<8;j++){ u16 h = f2bf(fv[j]); hs[j]=h; ls[j]=f2bf(fv[j]-bf2f(h)); }
        int G = (kk*BM + (r ^ (kk<<1)))*8;
        *(uint4*)&Ash[G] = make_uint4(pack2(hs[0],hs[1]),pack2(hs[2],hs[3]),pack2(hs[4],hs[5]),pack2(hs[6],hs[7]));
        *(uint4*)&Asl[G] = make_uint4(pack2(ls[0],ls[1]),pack2(ls[2],ls[3]),pack2(ls[4],ls[5]),pack2(ls[6],ls[7]));
      }
    }
    // ---- stage B ----
    {
      constexpr int BG = BN*4;
      #pragma unroll
      for (int i = 0; i < 2*BG/T; i++) {
        int g = tid + i*T;
        int gi = (g < BG) ? g : g - BG;
        int r = gi >> 2, kk = gi & 3;
        size_t ofs = (size_t)r*Kp + ks0 + kt + kk*8;
        int G = (kk*BN + (r ^ (kk<<1)))*8;
        if (g < BG) *(uint4*)&Bsh[G] = *(const uint4*)(Bh + ofs);
        else        *(uint4*)&Bsl[G] = *(const uint4*)(Bl + ofs);
      }
    }
    __syncthreads();
    // ---- frags + MFMA ----
    bf16x8 ah_[MI], al_[MI], bh_[NI], bl_[NI];
    #pragma unroll
    for (int mi=0;mi<MI;mi++){
      int rw = wrow*(MI*16) + mi*16 + fr;
      int G = (kg*BM + (rw ^ (kg<<1)))*8;
      ah_[mi] = *(const bf16x8*)&Ash[G];
      al_[mi] = *(const bf16x8*)&Asl[G];
    }
    #pragma unroll
    for (int ni=0;ni<NI;ni++){
      int cw = wcol*64 + ni*16 + fr;
      int G = (kg*BN + (cw ^ (kg<<1)))*8;
      bh_[ni] = *(const bf16x8*)&Bsh[G];
      bl_[ni] = *(const bf16x8*)&Bsl[G];
    }
    #pragma unroll
    for (int mi=0;mi<MI;mi++)
      #pragma unroll
      for (int ni=0;ni<NI;ni++){
        acc[mi][ni] = __builtin_amdgcn_mfma_f32_16x16x32_bf16(ah_[mi], bh_[ni], acc[mi][ni], 0,0,0);
        acc[mi][ni] = __builtin_amdgcn_mfma_f32_16x16x32_bf16(ah_[mi], bl_[ni], acc[mi][ni], 0,0,0);
        acc[mi][ni] = __builtin_amdgcn_mfma_f32_16x16x32_bf16(al_[mi], bh_[ni], acc[mi][ni], 0,0,0);
      }
    __syncthreads();
  }
  // ---- epilogue: D reg r -> row=(lane>>4)*4+r, col=lane&15 (m89-verified) ----
  float* Cb = (EPI==EPI_NONE) ? (C + (size_t)blockIdx.z*MP_USER*N) : C;
  #pragma unroll
  for (int mi=0;mi<MI;mi++){
    #pragma unroll
    for (int ni=0;ni<NI;ni++){
      int col = wcol*64 + ni*16 + fr;
      if (EPI!=EPI_NONE && col >= N) continue;
      #pragma unroll
      for (int r=0;r<4;r++){
        int row = row0 + wrow*(MI*16) + mi*16 + kg*4 + r;
        if (EPI!=EPI_NONE && row >= M) continue;
        size_t idx = (size_t)row*N + col;
        float v = acc[mi][ni][r];
        if (EPI==EPI_NONE)           Cb[idx] = v;
        else if (EPI==EPI_STORE)     Cb[idx] = v;
        else if (EPI==EPI_TANH)      Cb[idx] = tanhf(v + bias[col]);
        else if (EPI==EPI_LEAKY_ADD) Cb[idx] = leaky(v + bias[col]) + add[idx];
        else                         Cb[idx] += leaky(v + bias[col] + add[idx]);
      }
    }
  }
}

// ============ weight pre-split: W[K][N] fp32 -> Wt_hi/Wt_lo[Np][Kp] bf16 ============
struct WDesc { const float* w; u16 *th, *tl; int K, N, Kp, Np; };
struct WPack { WDesc d[12]; };
__global__ void split_w_k(WPack P)
{
  WDesc D = P.d[blockIdx.y];
  int gid = blockIdx.x*256 + threadIdx.x;
  int tot = D.Np * D.Kp;
  if (gid >= tot) return;
  int k = gid / D.Np, n = gid % D.Np;
  float v = (k < D.K && n < D.N) ? D.w[(size_t)k*D.N + n] : 0.f;
  u16 h = f2bf(v);
  D.th[(size_t)n*D.Kp + k] = h;
  D.tl[(size_t)n*D.Kp + k] = f2bf(v - bf2f(h));
}

// ---------------- graph structure ----------------
// doubled edges: src(e)=ei[e]; dst(e)= e<E ? ei[e+E] : ei[e-E]
__global__ void count_deg(const int* __restrict__ ei, int* __restrict__ deg, int E)
{
  int e = blockIdx.x*blockDim.x + threadIdx.x;
  if (e >= 2*E) return;
  int dst = (e < E) ? ei[e+E] : ei[e-E];
  atomicAdd(&deg[dst], 1);
}

// wave-scan version: 1024 elems/iter, 2 barriers/iter
__global__ void scan_rowptr(const int* __restrict__ deg, int* __restrict__ row_ptr, int n)
{
  __shared__ int wsum[4];
  __shared__ int carry;
  int tid = threadIdx.x, lane = tid & 63, wid = tid >> 6;
  if (tid==0) carry = 0;
  __syncthreads();
  for (int base=0; base<n; base+=1024) {
    int i0 = base + tid*4;
    int d[4];
    #pragma unroll
    for (int k=0;k<4;k++) d[k] = (i0+k < n) ? deg[i0+k] : 0;
    int t = d[0]+d[1]+d[2]+d[3];
    int incl = t;
    #pragma unroll
    for (int o=1;o<64;o<<=1){ int v = __shfl_up(incl, o); if (lane >= o) incl += v; }
    if (lane==63) wsum[wid] = incl;
    __syncthreads();
    int pre = carry;
    for (int w=0; w<wid; w++) pre += wsum[w];
    int run = pre + incl - t;
    #pragma unroll
    for (int k=0;k<4;k++){ run += d[k]; if (i0+k < n) row_ptr[i0+k+1] = run; }
    __syncthreads();
    if (tid==0) carry += wsum[0]+wsum[1]+wsum[2]+wsum[3];
  }
  if (tid==0) row_ptr[0] = 0;
}

__global__ void fill_csr(const int* __restrict__ ei, const int* __restrict__ row_ptr,
                         int* __restrict__ row_fill, int* __restrict__ col_src, int E)
{
  int e = blockIdx.x*blockDim.x + threadIdx.x;
  if (e >= 2*E) return;
  int src = ei[e];
  int dst = (e < E) ? ei[e+E] : ei[e-E];
  int pos = row_ptr[dst] + atomicAdd(&row_fill[dst], 1);
  col_src[pos] = src;
}

// guarded vector row load
template<int VW>
__device__ __forceinline__ void loadrow(const float* __restrict__ r, int c0, int L, float* v){
  if (c0 + VW <= L) {
    if (VW==4) *(float4*)v = *(const float4*)r;
    else       *(float2*)v = *(const float2*)r;
  } else {
    #pragma unroll
    for (int j=0;j<VW;j++) v[j] = (c0+j < L) ? r[j] : 0.f;
  }
}

// ---------------- l2norm + bf16 split; folds mlp partial-sum reduce (nchunk, fixed
// order -> deterministic) + bias + tanh ----------------
// rows < NUSER: from pref; rows [NUSER,NNODE): tanh(sum_z xp_z + bias); pad rows: zero
template<int VW>
__global__ __launch_bounds__(256)
void l2norm_split_k(const float* __restrict__ pref, const float* __restrict__ xp,
                    const float* __restrict__ bias,
                    u16* __restrict__ xh, u16* __restrict__ xl, int L, int Kp, int nchunk)
{
  int row = (blockIdx.x*blockDim.x + threadIdx.x) >> 6;
  int lane = threadIdx.x & 63;
  if (row >= MP_NODE) return;
  int c0 = lane*VW;
  size_t ofs = (size_t)row*Kp + c0;
  if (row >= NNODE) {
    if (VW==4) { *(uint2*)&xh[ofs] = make_uint2(0,0); *(uint2*)&xl[ofs] = make_uint2(0,0); }
    else       { *(unsigned*)&xh[ofs] = 0; *(unsigned*)&xl[ofs] = 0; }
    return;
  }
  float v[VW];
  if (row < NUSER) {
    loadrow<VW>(pref + (size_t)row*L + c0, c0, L, v);
  } else {
    int i = row - NUSER;
    size_t po = (size_t)i*Kp + c0;   // xp padded to Kp cols, MP_USER rows per chunk
    float s[VW] = {};
    for (int z = 0; z < nchunk; z++) {
      float a[VW];
      const float* src = xp + (size_t)z*MP_USER*Kp + po;
      if (VW==4) *(float4*)a = *(const float4*)src;
      else       *(float2*)a = *(const float2*)src;
      #pragma unroll
      for (int j=0;j<VW;j++) s[j] += a[j];
    }
    #pragma unroll
    for (int j=0;j<VW;j++){
      int c = c0+j;
      float t = s[j] + ((c<L) ? bias[c] : 0.f);
      v[j] = (c<L) ? tanhf(t) : 0.f;
    }
  }
  float ss = 0.f;
  #pragma unroll
  for (int j=0;j<VW;j++) ss += v[j]*v[j];
  #pragma unroll
  for (int o=32;o;o>>=1) ss += __shfl_xor(ss, o);
  float inv = 1.0f / fmaxf(sqrtf(ss), 1e-12f);
  u16 hs[VW], ls[VW];
  #pragma unroll
  for (int j=0;j<VW;j++){
    float val = (c0+j < L) ? v[j]*inv : 0.f;
    hs[j] = f2bf(val); ls[j] = f2bf(val - bf2f(hs[j]));
  }
  if (VW==4) { *(uint2*)&xh[ofs] = make_uint2(pack2(hs[0],hs[1]),pack2(hs[2],hs[3]));
               *(uint2*)&xl[ofs] = make_uint2(pack2(ls[0],ls[1]),pack2(ls[2],ls[3])); }
  else       { *(unsigned*)&xh[ofs] = pack2(hs[0],hs[1]); *(unsigned*)&xl[ofs] = pack2(ls[0],ls[1]); }
}

// ============ fused edge phase (R5): online-softmax, zero LDS ============
// One wave per dst node; 4 edges in parallel (16 lanes/edge). Each subwave keeps
// its edge's xw[src] row in REGISTERS (KCH float4) and maintains flash-style
// online-softmax state (m, d, acc): acc = acc*e^{m-m'} + e^{lg-m'}*row. After the
// CSR loop, 2 shfl_xor merge rounds (off 16,32) combine subwave states; agg=acc/d.
// Each gathered row is read EXACTLY once; no logits/alpha round-trips; no LDS ->
// no occupancy cap (R4's 50KB cache -> 25% occ was the regression driver).
// m sentinel -1e30: a never-valid subwave keeps m=-1e30 (its possibly-spurious d
// is annihilated at merge by exp(-1e30-finite)=0; cnt>0 guarantees subwave 0 is
// finite); cnt=0 skips the loop -> d=0 -> agg=0 (matches old aggregate_k).
// Same exp/sigmoid formulas as reference; only fp re-association differs.
template<int KCH>   // KCH = Kp/64 chunks of 64 floats; lane j covers c=j*4+k*64
__global__ __launch_bounds__(256)
void fused_edge_k(const float* __restrict__ xw, const int* __restrict__ row_ptr,
                  const int* __restrict__ col_src, const int* __restrict__ deg_,
                  const float* __restrict__ bias,
                  u16* __restrict__ hh, u16* __restrict__ hl, int L, int Kp)
{
  const int lane = threadIdx.x & 63;
  const int node = blockIdx.x*4 + (threadIdx.x >> 6);
  if (node >= MP_NODE) return;
  const int sw = lane >> 4, j = lane & 15;

  if (node >= NNODE) {   // pad rows: zero full Kp row
    if (sw == 0) {
      #pragma unroll
      for (int k=0;k<KCH;k++){
        int c = j*4 + k*64;
        *(uint2*)&hh[(size_t)node*Kp + c] = make_uint2(0,0);
        *(uint2*)&hl[(size_t)node*Kp + c] = make_uint2(0,0);
      }
    }
    return;
  }
  const int s = row_ptr[node], e = row_ptr[node+1];
  const int cnt = e - s;

  // dst row chunks (same values the old edge_logits read)
  const float* pd = xw + (size_t)node*L;
  float4 pdv[KCH];
  #pragma unroll
  for (int k=0;k<KCH;k++){
    int c = j*4 + k*64;
    pdv[k] = (c < L) ? *(const float4*)(pd + c) : make_float4(0.f,0.f,0.f,0.f);
  }

  float m = -1e30f, d = 0.f;
  float4 acc[KCH];
  #pragma unroll
  for (int k=0;k<KCH;k++) acc[k] = make_float4(0.f,0.f,0.f,0.f);

  const int nit = (cnt + 3) >> 2;
  for (int it = 0; it < nit; it++) {
    int i = it*4 + sw;
    bool valid = (i < cnt);
    float4 row[KCH];
    #pragma unroll
    for (int k=0;k<KCH;k++) row[k] = make_float4(0.f,0.f,0.f,0.f);
    float dot = 0.f;
    int src = 0;
    if (valid) {
      src = col_src[s+i];
      const float* ps = xw + (size_t)src*L;
      #pragma unroll
      for (int k=0;k<KCH;k++){
        int c = j*4 + k*64;
        if (c < L) {
          row[k] = *(const float4*)(ps + c);
          dot += row[k].x*pdv[k].x + row[k].y*pdv[k].y + row[k].z*pdv[k].z + row[k].w*pdv[k].w;
        }
      }
    }
    #pragma unroll
    for (int o=8;o;o>>=1) dot += __shfl_xor(dot, o, 16);
    float lg = -1e30f;
    if (valid) {
      float t = dot / sqrtf((float)deg_[src]);
      float gate = 1.0f/(1.0f + expf(-t));
      lg = dot * gate;
    }
    // online-softmax update (invalid with finite m: w = exp(-1e30-m) = 0, row = 0)
    float mn = fmaxf(m, lg);
    float sc = expf(m - mn);
    float w  = expf(lg - mn);
    d = d*sc + w;
    #pragma unroll
    for (int k=0;k<KCH;k++){
      acc[k].x = acc[k].x*sc + w*row[k].x;
      acc[k].y = acc[k].y*sc + w*row[k].y;
      acc[k].z = acc[k].z*sc + w*row[k].z;
      acc[k].w = acc[k].w*sc + w*row[k].w;
    }
    m = mn;
  }

  // merge the 4 subwave states (lanes j, j+16, j+32, j+48)
  #pragma unroll
  for (int off=16; off<=32; off<<=1) {
    float m2 = __shfl_xor(m, off);
    float d2 = __shfl_xor(d, off);
    float4 a2[KCH];
    #pragma unroll
    for (int k=0;k<KCH;k++){
      a2[k].x = __shfl_xor(acc[k].x, off);
      a2[k].y = __shfl_xor(acc[k].y, off);
      a2[k].z = __shfl_xor(acc[k].z, off);
      a2[k].w = __shfl_xor(acc[k].w, off);
    }
    float mn = fmaxf(m, m2);
    float s1 = expf(m - mn), s2 = expf(m2 - mn);
    d = d*s1 + d2*s2;
    #pragma unroll
    for (int k=0;k<KCH;k++){
      acc[k].x = acc[k].x*s1 + a2[k].x*s2;
      acc[k].y = acc[k].y*s1 + a2[k].y*s2;
      acc[k].z = acc[k].z*s1 + a2[k].z*s2;
      acc[k].w = acc[k].w*s1 + a2[k].w*s2;
    }
    m = mn;
  }

  float dinv = 1.0f / fmaxf(d, 1e-16f);   // cnt=0: acc=0 -> agg=0

  // tail: bias + l2norm + leaky + bf16 split (per-chunk layout c=j*4+k*64)
  float ss = 0.f;
  float4 tv[KCH];
  #pragma unroll
  for (int k=0;k<KCH;k++){
    int c = j*4 + k*64;
    if (c < L) {
      float4 bv = *(const float4*)(bias + c);
      tv[k].x = acc[k].x*dinv + bv.x;
      tv[k].y = acc[k].y*dinv + bv.y;
      tv[k].z = acc[k].z*dinv + bv.z;
      tv[k].w = acc[k].w*dinv + bv.w;
    } else {
      tv[k] = make_float4(0.f,0.f,0.f,0.f);
    }
    ss += tv[k].x*tv[k].x + tv[k].y*tv[k].y + tv[k].z*tv[k].z + tv[k].w*tv[k].w;
  }
  #pragma unroll
  for (int o=1;o<16;o<<=1) ss += __shfl_xor(ss, o, 16);
  float inv = 1.0f / fmaxf(sqrtf(ss), 1e-12f);
  if (sw == 0) {
    #pragma unroll
    for (int k=0;k<KCH;k++){
      int c = j*4 + k*64;
      float o0 = leaky(tv[k].x*inv), o1 = leaky(tv[k].y*inv);
      float o2 = leaky(tv[k].z*inv), o3 = leaky(tv[k].w*inv);
      u16 h0=f2bf(o0), h1=f2bf(o1), h2=f2bf(o2), h3=f2bf(o3);
      u16 l0=f2bf(o0-bf2f(h0)), l1=f2bf(o1-bf2f(h1)), l2=f2bf(o2-bf2f(h2)), l3=f2bf(o3-bf2f(h3));
      *(uint2*)&hh[(size_t)node*Kp + c] = make_uint2(pack2(h0,h1), pack2(h2,h3));
      *(uint2*)&hl[(size_t)node*Kp + c] = make_uint2(pack2(l0,l1), pack2(l2,l3));
    }
  }
}

// scores: rep holds 3*rep_true -> scale dot by 1/9
__global__ __launch_bounds__(256)
void score_k(const float* __restrict__ rep, const int* __restrict__ un,
             const int* __restrict__ pi, const int* __restrict__ ni, float* __restrict__ out)
{
  int wid = (blockIdx.x*blockDim.x + threadIdx.x) >> 6;
  int lane = threadIdx.x & 63;
  if (wid >= 2048) return;
  int i = wid & 1023;
  int isneg = wid >> 10;
  int u = un[i];
  int it = isneg ? ni[i] : pi[i];
  float p = rep[(size_t)u*64 + lane] * rep[(size_t)it*64 + lane];
  #pragma unroll
  for (int o=32;o;o>>=1) p += __shfl_xor(p, o);
  if (lane==0) out[isneg*1024 + i] = p * (1.0f/9.0f);
}

// ---------------- launch ----------------
static inline size_t align_up(size_t v){ return (v + 255) & ~(size_t)255; }
static inline int cdiv(int a, int b){ return (a + b - 1) / b; }

extern "C" void kernel_launch(void* const* d_in, const int* in_sizes, int n_in,
                              void* d_out, int out_size, void* d_ws, size_t ws_size,
                              hipStream_t stream)
{
  const int E  = in_sizes[31] / 2;   // 250000
  const int E2 = 2*E;

  char* p = (char*)d_ws;
  auto carve = [&](size_t bytes){ char* r = p; p += align_up(bytes); return r; };
  // xp (split-K partials, up to 4 chunks) is dead before the conv GEMM writes xw,
  // so they alias: one 82.3MB union region.
  float* xw     = (float*)carve((size_t)4*MP_USER*256*4);
  float* xp     = xw;
  u16*   xh     = (u16*)carve((size_t)MP_NODE*256*2);
  u16*   xl     = (u16*)carve((size_t)MP_NODE*256*2);
  float* xhat   = (float*)carve((size_t)NNODE*64*4);
  float* rep    = (float*)carve((size_t)NNODE*64*4);
  int* deg      = (int*)carve((size_t)NNODE*4);
  int* row_ptr  = (int*)carve((size_t)(NNODE+1)*4);
  int* row_fill = (int*)carve((size_t)NNODE*4);
  int* col_src  = (int*)carve((size_t)E2*4);

  const int* ei = (const int*)d_in[31];
  const float* id_emb = (const float*)d_in[30];

  struct Mod { const float *feat,*pref,*mlp_w,*mlp_b,*conv_w,*conv_b,*lin_w,*lin_b,*g_w,*g_b;
               int Fd, L, Kpx, Kpf, NpL; };
  Mod md[3];
  for (int m=0;m<3;m++) {
    int b = m*10;
    md[m].feat   = (const float*)d_in[b+0];
    md[m].pref   = (const float*)d_in[b+1];
    md[m].mlp_w  = (const float*)d_in[b+2];
    md[m].mlp_b  = (const float*)d_in[b+3];
    md[m].conv_w = (const float*)d_in[b+4];
    md[m].conv_b = (const float*)d_in[b+5];
    md[m].lin_w  = (const float*)d_in[b+6];
    md[m].lin_b  = (const float*)d_in[b+7];
    md[m].g_w    = (const float*)d_in[b+8];
    md[m].g_b    = (const float*)d_in[b+9];
  }
  md[0].Fd=2048; md[0].L=256; md[0].Kpx=256; md[0].Kpf=2048; md[0].NpL=256;
  md[1].Fd=128;  md[1].L=128; md[1].Kpx=128; md[1].Kpf=128;  md[1].NpL=128;
  md[2].Fd=100;  md[2].L=100; md[2].Kpx=128; md[2].Kpf=128;  md[2].NpL=128;

  u16 *wmh[3],*wml[3],*wch[3],*wcl[3],*wlh[3],*wll[3],*wgh[3],*wgl[3];
  WPack P;
  int maxTot = 0;
  for (int m=0;m<3;m++) {
    const Mod& M_ = md[m];
    size_t smlp = (size_t)M_.NpL*M_.Kpf*2, sconv = (size_t)M_.NpL*M_.Kpx*2, slin = (size_t)64*M_.Kpx*2;
    wmh[m]=(u16*)carve(smlp); wml[m]=(u16*)carve(smlp);
    wch[m]=(u16*)carve(sconv); wcl[m]=(u16*)carve(sconv);
    wlh[m]=(u16*)carve(slin);  wll[m]=(u16*)carve(slin);
    wgh[m]=(u16*)carve(slin);  wgl[m]=(u16*)carve(slin);
    P.d[m*4+0] = { M_.mlp_w,  wmh[m], wml[m], M_.Fd, M_.L, M_.Kpf, M_.NpL };
    P.d[m*4+1] = { M_.conv_w, wch[m], wcl[m], M_.L,  M_.L, M_.Kpx, M_.NpL };
    P.d[m*4+2] = { M_.lin_w,  wlh[m], wll[m], M_.L,  64,   M_.Kpx, 64 };
    P.d[m*4+3] = { M_.g_w,    wgh[m], wgl[m], M_.L,  64,   M_.Kpx, 64 };
    for (int q=0;q<4;q++){ int t = P.d[m*4+q].Np*P.d[m*4+q].Kp; if (t>maxTot) maxTot=t; }
  }

  hipMemsetAsync(deg, 0, (size_t)NNODE*4, stream);
  hipMemsetAsync(row_fill, 0, (size_t)NNODE*4, stream);
  hipMemsetAsync(rep, 0, (size_t)NNODE*64*4, stream);

  { dim3 g(cdiv(maxTot,256), 12); split_w_k<<<g,256,0,stream>>>(P); }
  {
    int blocks = cdiv(E2, 256);
    count_deg<<<blocks,256,0,stream>>>(ei, deg, E);
    scan_rowptr<<<1,256,0,stream>>>(deg, row_ptr, NNODE);
    fill_csr<<<blocks,256,0,stream>>>(ei, row_ptr, row_fill, col_src, E);
  }

  for (int m=0;m<3;m++) {
    const Mod& M_ = md[m];
    const int L = M_.L;

    // mlp partials: xp[chunk] = feat @ mlp_w (chunk of K); SPLITK boosts occupancy
    if (m == 0)
      wgemm_k<1,4,4,EPI_NONE,false,4><<<dim3(1,MP_USER/64,4),256,0,stream>>>(
          M_.feat, nullptr, nullptr, wmh[m], wml[m], nullptr, nullptr,
          xp, NUSER, 256, M_.Fd, M_.Kpf);
    else
      wgemm_k<1,2,4,EPI_NONE,false,2><<<dim3(1,MP_USER/64,2),128,0,stream>>>(
          M_.feat, nullptr, nullptr, wmh[m], wml[m], nullptr, nullptr,
          xp, NUSER, 128, M_.Fd, M_.Kpf);

    // l2norm + reduce partials + bias + tanh -> xh/xl
    {
      int nchunk = (m==0) ? 4 : 2;
      if (M_.Kpx==256) l2norm_split_k<4><<<MP_NODE/4,256,0,stream>>>(M_.pref, xp, M_.mlp_b, xh, xl, L, M_.Kpx, nchunk);
      else             l2norm_split_k<2><<<MP_NODE/4,256,0,stream>>>(M_.pref, xp, M_.mlp_b, xh, xl, L, M_.Kpx, nchunk);
    }

    // xw = x @ conv_w
    if (m == 0)
      wgemm_k<1,4,4,EPI_STORE,true,1><<<dim3(1,MP_NODE/64,1),256,0,stream>>>(
          nullptr, xh, xl, wch[m], wcl[m], nullptr, nullptr, xw, NNODE, L, L, M_.Kpx);
    else
      wgemm_k<1,2,4,EPI_STORE,true,1><<<dim3(1,MP_NODE/64,1),128,0,stream>>>(
          nullptr, xh, xl, wch[m], wcl[m], nullptr, nullptr, xw, NNODE, L, L, M_.Kpx);

    // xhat = leaky(x @ lin_w + b) + id_emb
    wgemm_k<4,1,2,EPI_LEAKY_ADD,true,1><<<dim3(1,MP_NODE/128,1),256,0,stream>>>(
        nullptr, xh, xl, wlh[m], wll[m], M_.lin_b, id_emb, xhat, NNODE, 64, L, M_.Kpx);

    // fused edge phase: online-softmax logits+aggregate -> h (xh/xl), zero LDS
    if (m == 0)
      fused_edge_k<4><<<MP_NODE/4,256,0,stream>>>(xw, row_ptr, col_src, deg, M_.conv_b, xh, xl, L, M_.Kpx);
    else
      fused_edge_k<2><<<MP_NODE/4,256,0,stream>>>(xw, row_ptr, col_src, deg, M_.conv_b, xh, xl, L, M_.Kpx);

    // rep += leaky(h @ g_w + g_b + xhat)
    wgemm_k<4,1,2,EPI_ACCUM,true,1><<<dim3(1,MP_NODE/128,1),256,0,stream>>>(
        nullptr, xh, xl, wgh[m], wgl[m], M_.g_b, xhat, rep, NNODE, 64, L, M_.Kpx);
  }

  score_k<<<cdiv(2048*64,256),256,0,stream>>>(rep, (const int*)d_in[32], (const int*)d_in[33],
                                              (const int*)d_in[34], (float*)d_out);
}